// Round 12
// baseline (97913.489 us; speedup 1.0000x reference)
//
#include <hip/hip_runtime.h>

// Persistent diagonal-pipelined GRU. r11 base (all weights bf16 in LDS,
// fence-free MALL sync) split 2x for occupancy: 512 blocks x 512 threads,
// 2 j-rows/block, LDS 80,896 B -> 2 blocks/CU = 16 waves/CU (4/SIMD), double
// r11's latency hiding. Weight reads ds_read_b128; phase-1 sweeps fully
// unrolled (32 outstanding sc1 loads, one drain per sweep).

#ifndef __has_builtin
#define __has_builtin(x) 0
#endif
#if __has_builtin(__builtin_amdgcn_fdot2_f32_bf16)
#define HAS_DOT2 1
typedef __bf16 bf16x2 __attribute__((ext_vector_type(2)));
#else
#define HAS_DOT2 0
#endif

struct GruParams {
  const float* x;            // (32, 512, 128)
  const float* Wx[3][3];     // [layer][gate z,r,g]
  const float* Wh[3][3];
  const float* bias[3][3];
  const float* Wout;         // (128, 1024)
  const float* bout;         // (128)
  unsigned* hP;              // [3][512 kp][32 b] packed bf16 pairs (j-pairs)
  unsigned* rhP;             // same layout
  float* hF;                 // [3][1024 j][32 b] f32 (owner-thread-private)
  unsigned* bar;
  float* out;                // (B,S,O)
  float* outHid;             // (B,L,H)
};

// LDS dwords: 15 weight slices x 1024 (2 rows x 512 kp) + scratch 8 waves x 608
// slices: s = l*3+gate for Wh (s=0..8), 9..11 = Wx1 z/r/g, 12..14 = Wx2 z/r/g
#define SCRO 15360
#define LDSB ((15360 + 8 * 608) * 4)    // 80,896 B -> 2 blocks/CU

extern __shared__ unsigned lds_u[];

__device__ __forceinline__ unsigned loadcu(const unsigned* p_) {
  return __hip_atomic_load(p_, __ATOMIC_RELAXED, __HIP_MEMORY_SCOPE_AGENT);
}
__device__ __forceinline__ void storecu(unsigned* p_, unsigned v) {
  __hip_atomic_store(p_, v, __ATOMIC_RELAXED, __HIP_MEMORY_SCOPE_AGENT);
}
__device__ __forceinline__ unsigned short f2bfu(float f) {   // RNE
  union { float f; unsigned u; } c; c.f = f;
  unsigned r = c.u + 0x7fffu + ((c.u >> 16) & 1u);
  return (unsigned short)(r >> 16);
}
__device__ __forceinline__ unsigned pack2(float f0, float f1) {
  return ((unsigned)f2bfu(f1) << 16) | (unsigned)f2bfu(f0);
}
__device__ __forceinline__ float blo(unsigned u) {
  union { unsigned i; float f; } c; c.i = u << 16; return c.f;
}
__device__ __forceinline__ float bhi(unsigned u) {
  union { unsigned i; float f; } c; c.i = u & 0xffff0000u; return c.f;
}
__device__ __forceinline__ float d2(float acc, unsigned a, unsigned wgt) {
#if HAS_DOT2
  return __builtin_amdgcn_fdot2_f32_bf16(__builtin_bit_cast(bf16x2, a),
                                         __builtin_bit_cast(bf16x2, wgt),
                                         acc, false);
#else
  return acc + blo(a) * blo(wgt) + bhi(a) * bhi(wgt);
#endif
}
// acc += dot of 4 packed-act dwords against one uint4 weight read
__device__ __forceinline__ float d8(float acc, unsigned a0, unsigned a1,
                                    unsigned a2, unsigned a3, const uint4 wv) {
  return d2(d2(d2(d2(acc, a0, wv.x), a1, wv.y), a2, wv.z), a3, wv.w);
}

// Two-level barrier over 512 blocks: 32 groups x 16, 128B-strided lines.
__device__ __forceinline__ void gridbar(unsigned* bar, unsigned phase, int bid) {
  __syncthreads();
  if (threadIdx.x == 0) {
    const int g = bid & 31;
    unsigned* grp   = bar + (g << 5);
    unsigned* root  = bar + 1024;
    unsigned* go    = bar + 1056;
    unsigned* grpGo = bar + 1088 + (g << 5);
    const unsigned gt = phase * 16u;
    const unsigned rt = phase * 32u;
    unsigned old = __hip_atomic_fetch_add(grp, 1u, __ATOMIC_RELAXED, __HIP_MEMORY_SCOPE_AGENT);
    if (old == gt - 1u) {
      unsigned r = __hip_atomic_fetch_add(root, 1u, __ATOMIC_RELAXED, __HIP_MEMORY_SCOPE_AGENT);
      if (r == rt - 1u)
        __hip_atomic_store(go, phase, __ATOMIC_RELAXED, __HIP_MEMORY_SCOPE_AGENT);
      while (__hip_atomic_load(go, __ATOMIC_RELAXED, __HIP_MEMORY_SCOPE_AGENT) < phase)
        __builtin_amdgcn_s_sleep(2);
      __hip_atomic_store(grpGo, phase, __ATOMIC_RELAXED, __HIP_MEMORY_SCOPE_AGENT);
    } else {
      while (__hip_atomic_load(grpGo, __ATOMIC_RELAXED, __HIP_MEMORY_SCOPE_AGENT) < phase)
        __builtin_amdgcn_s_sleep(2);
    }
  }
  __syncthreads();
}

__global__ __launch_bounds__(512, 4) void gruPersist(GruParams p) {
  const int tid  = threadIdx.x;
  const int bid  = blockIdx.x;
  const int w    = tid >> 6;        // wave 0..7
  const int lane = tid & 63;
  const int b    = lane & 31;
  const int ks   = lane >> 5;
  float* scratch = (float*)(lds_u + SCRO);
  float* my      = scratch + w * 608;

  // ---- one-time: convert this block's 2 j-rows of weights -> packed bf16 ----
  for (int d = tid; d < 15360; d += 512) {
    const int s = d >> 10, rem = d & 1023;
    const int jj = rem >> 9, kp = rem & 511;
    const float* src;
    if (s < 9)       src = p.Wh[s / 3][s % 3];
    else if (s < 12) src = p.Wx[1][s - 9];
    else             src = p.Wx[2][s - 12];
    const size_t base = (size_t)((bid << 1) + jj) * 1024 + (size_t)(kp << 1);
    lds_u[d] = pack2(src[base], src[base + 1]);
  }
  __syncthreads();

  unsigned* hP0 = p.hP;            unsigned* hP1 = p.hP + 16384;
  unsigned* hP2 = p.hP + 32768;
  unsigned* rq0 = p.rhP;           unsigned* rq1 = p.rhP + 16384;
  unsigned* rq2 = p.rhP + 32768;

  unsigned phase = 0;
  float my_z[3][2], my_gx[3][2];
  #pragma unroll
  for (int l = 0; l < 3; ++l) { my_z[l][0]=my_z[l][1]=my_gx[l][0]=my_gx[l][1]=0.f; }

  for (int m = 0; m < 514; ++m) {
    const bool act0 = (m < 512);
    const bool act1 = (m >= 1 && m <= 512);
    const bool act2 = (m >= 2 && m <= 513);
    const int t0 = m, t1 = m - 1, t2 = m - 2, th = m - 3;

    // ===================== phase 1: all A dots ============================
    float a0z[2]={0,0}, a0r[2]={0,0}, a0g[2]={0,0};
    float a1z[2]={0,0}, a1r[2]={0,0}, a1g[2]={0,0};
    float a2z[2]={0,0}, a2r[2]={0,0}, a2g[2]={0,0};
    float ah = 0.f;

    if (act0) {   // l0 x-side (K=128, f32): wave w owns k [16w,16w+16)
      const float* xb = p.x + ((size_t)b << 16) + ((size_t)t0 << 7);
      #pragma unroll
      for (int i = 0; i < 2; ++i) {
        const int k = (w << 4) + (i << 3) + (ks << 2);
        const float4 xv = *(const float4*)(xb + k);
        #pragma unroll
        for (int jj = 0; jj < 2; ++jj) {
          const size_t row = (size_t)((bid << 1) + jj) * 128 + k;
          const float4 wz = *(const float4*)(p.Wx[0][0] + row);
          const float4 wr = *(const float4*)(p.Wx[0][1] + row);
          const float4 wg = *(const float4*)(p.Wx[0][2] + row);
          a0z[jj] += xv.x*wz.x + xv.y*wz.y + xv.z*wz.z + xv.w*wz.w;
          a0r[jj] += xv.x*wr.x + xv.y*wr.y + xv.z*wr.z + xv.w*wr.w;
          a0g[jj] += xv.x*wg.x + xv.y*wg.y + xv.z*wg.z + xv.w*wg.w;
        }
      }
    }

    // sweep1 over h0: l0 z/r (Wh0) + l1 z/r/g (Wx1). wave owns 64 kp.
    #pragma unroll
    for (int i = 0; i < 8; ++i) {
      const int kp0 = (w << 6) + (i << 3) + (ks << 2);
      const unsigned a0 = loadcu(hP0 + (kp0+0)*32 + b);
      const unsigned a1 = loadcu(hP0 + (kp0+1)*32 + b);
      const unsigned a2 = loadcu(hP0 + (kp0+2)*32 + b);
      const unsigned a3 = loadcu(hP0 + (kp0+3)*32 + b);
      #pragma unroll
      for (int jj = 0; jj < 2; ++jj) {
        const int wo = (jj << 9) + kp0;
        a0z[jj] = d8(a0z[jj], a0,a1,a2,a3, *(const uint4*)(lds_u +  0*1024 + wo));
        a0r[jj] = d8(a0r[jj], a0,a1,a2,a3, *(const uint4*)(lds_u +  1*1024 + wo));
        a1z[jj] = d8(a1z[jj], a0,a1,a2,a3, *(const uint4*)(lds_u +  9*1024 + wo));
        a1r[jj] = d8(a1r[jj], a0,a1,a2,a3, *(const uint4*)(lds_u + 10*1024 + wo));
        a1g[jj] = d8(a1g[jj], a0,a1,a2,a3, *(const uint4*)(lds_u + 11*1024 + wo));
      }
    }
    #pragma unroll
    for (int jj = 0; jj < 2; ++jj) {
      a0z[jj] += __shfl_xor(a0z[jj], 32);
      a0r[jj] += __shfl_xor(a0r[jj], 32);
      a0g[jj] += __shfl_xor(a0g[jj], 32);
      a1g[jj] += __shfl_xor(a1g[jj], 32);
    }
    if (ks == 0) {
      #pragma unroll
      for (int jj = 0; jj < 2; ++jj) {
        my[(0*2+jj)*32 + b] = a0z[jj];
        my[(1*2+jj)*32 + b] = a0r[jj];
        my[(2*2+jj)*32 + b] = a0g[jj];
        my[(5*2+jj)*32 + b] = a1g[jj];
      }
    }

    // sweep2 over h1: l1 z/r (Wh1) + l2 z/r/g (Wx2)
    #pragma unroll
    for (int i = 0; i < 8; ++i) {
      const int kp0 = (w << 6) + (i << 3) + (ks << 2);
      const unsigned a0 = loadcu(hP1 + (kp0+0)*32 + b);
      const unsigned a1 = loadcu(hP1 + (kp0+1)*32 + b);
      const unsigned a2 = loadcu(hP1 + (kp0+2)*32 + b);
      const unsigned a3 = loadcu(hP1 + (kp0+3)*32 + b);
      #pragma unroll
      for (int jj = 0; jj < 2; ++jj) {
        const int wo = (jj << 9) + kp0;
        a1z[jj] = d8(a1z[jj], a0,a1,a2,a3, *(const uint4*)(lds_u +  3*1024 + wo));
        a1r[jj] = d8(a1r[jj], a0,a1,a2,a3, *(const uint4*)(lds_u +  4*1024 + wo));
        a2z[jj] = d8(a2z[jj], a0,a1,a2,a3, *(const uint4*)(lds_u + 12*1024 + wo));
        a2r[jj] = d8(a2r[jj], a0,a1,a2,a3, *(const uint4*)(lds_u + 13*1024 + wo));
        a2g[jj] = d8(a2g[jj], a0,a1,a2,a3, *(const uint4*)(lds_u + 14*1024 + wo));
      }
    }
    #pragma unroll
    for (int jj = 0; jj < 2; ++jj) {
      a1z[jj] += __shfl_xor(a1z[jj], 32);
      a1r[jj] += __shfl_xor(a1r[jj], 32);
      a2g[jj] += __shfl_xor(a2g[jj], 32);
    }
    if (ks == 0) {
      #pragma unroll
      for (int jj = 0; jj < 2; ++jj) {
        my[(3*2+jj)*32 + b] = a1z[jj];
        my[(4*2+jj)*32 + b] = a1r[jj];
        my[(8*2+jj)*32 + b] = a2g[jj];
      }
    }

    // sweep3 over h2: l2 z/r (Wh2) + head (bid<128: Wout row bid, f32 L2)
    #pragma unroll
    for (int i = 0; i < 8; ++i) {
      const int kp0 = (w << 6) + (i << 3) + (ks << 2);
      const unsigned a0 = loadcu(hP2 + (kp0+0)*32 + b);
      const unsigned a1 = loadcu(hP2 + (kp0+1)*32 + b);
      const unsigned a2 = loadcu(hP2 + (kp0+2)*32 + b);
      const unsigned a3 = loadcu(hP2 + (kp0+3)*32 + b);
      #pragma unroll
      for (int jj = 0; jj < 2; ++jj) {
        const int wo = (jj << 9) + kp0;
        a2z[jj] = d8(a2z[jj], a0,a1,a2,a3, *(const uint4*)(lds_u + 6*1024 + wo));
        a2r[jj] = d8(a2r[jj], a0,a1,a2,a3, *(const uint4*)(lds_u + 7*1024 + wo));
      }
      if (bid < 128) {
        const float* wrow = p.Wout + ((size_t)bid << 10) + (kp0 << 1);
        const float4 w0 = *(const float4*)(wrow);
        const float4 w1 = *(const float4*)(wrow + 4);
        ah += blo(a0)*w0.x + bhi(a0)*w0.y + blo(a1)*w0.z + bhi(a1)*w0.w;
        ah += blo(a2)*w1.x + bhi(a2)*w1.y + blo(a3)*w1.z + bhi(a3)*w1.w;
      }
    }
    #pragma unroll
    for (int jj = 0; jj < 2; ++jj) {
      a2z[jj] += __shfl_xor(a2z[jj], 32);
      a2r[jj] += __shfl_xor(a2r[jj], 32);
    }
    ah += __shfl_xor(ah, 32);
    if (ks == 0) {
      #pragma unroll
      for (int jj = 0; jj < 2; ++jj) {
        my[(6*2+jj)*32 + b] = a2z[jj];
        my[(7*2+jj)*32 + b] = a2r[jj];
      }
      my[576 + b] = ah;
    }

    __syncthreads();
    // epilogue A: tid<32 owns batch bb=tid, both j-rows of this block
    if (tid < 32) {
      const int bb = tid;
      #pragma unroll
      for (int l = 0; l < 3; ++l) {
        float rr[2];
        #pragma unroll
        for (int q = 0; q < 2; ++q) {
          float sz = 0.f, sr = 0.f, sg = 0.f;
          #pragma unroll
          for (int ww = 0; ww < 8; ++ww) {
            sz += scratch[ww * 608 + ((l*3+0)*2 + q)*32 + bb];
            sr += scratch[ww * 608 + ((l*3+1)*2 + q)*32 + bb];
            sg += scratch[ww * 608 + ((l*3+2)*2 + q)*32 + bb];
          }
          const int j = (bid << 1) + q;
          const float zp = sz + p.bias[l][0][j];
          const float rp = sr + p.bias[l][1][j];
          my_gx[l][q] = sg + p.bias[l][2][j];
          my_z[l][q]  = 1.f / (1.f + expf(-zp));
          const float r = 1.f / (1.f + expf(-rp));
          rr[q] = r * p.hF[l * 32768 + j * 32 + bb];
        }
        unsigned* rq = (l == 0) ? rq0 : (l == 1) ? rq1 : rq2;
        storecu(rq + bid * 32 + bb, pack2(rr[0], rr[1]));
      }
    }
    if (m >= 3 && bid < 128 && tid < 32) {
      float s = 0.f;
      #pragma unroll
      for (int ww = 0; ww < 8; ++ww) s += scratch[ww * 608 + 576 + tid];
      p.out[((size_t)tid << 16) + ((size_t)th << 7) + bid] = s + p.bout[bid];
    }

    ++phase; gridbar(p.bar, phase, bid);

    // ===================== phase 2: fused C ===============================
    float c0[2]={0,0}, c1[2]={0,0}, c2[2]={0,0};
    #pragma unroll 4
    for (int i = 0; i < 8; ++i) {
      const int kp0 = (w << 6) + (i << 3) + (ks << 2);
      const unsigned r00 = loadcu(rq0 + (kp0+0)*32 + b);
      const unsigned r01 = loadcu(rq0 + (kp0+1)*32 + b);
      const unsigned r02 = loadcu(rq0 + (kp0+2)*32 + b);
      const unsigned r03 = loadcu(rq0 + (kp0+3)*32 + b);
      const unsigned r10 = loadcu(rq1 + (kp0+0)*32 + b);
      const unsigned r11 = loadcu(rq1 + (kp0+1)*32 + b);
      const unsigned r12 = loadcu(rq1 + (kp0+2)*32 + b);
      const unsigned r13 = loadcu(rq1 + (kp0+3)*32 + b);
      const unsigned r20 = loadcu(rq2 + (kp0+0)*32 + b);
      const unsigned r21 = loadcu(rq2 + (kp0+1)*32 + b);
      const unsigned r22 = loadcu(rq2 + (kp0+2)*32 + b);
      const unsigned r23 = loadcu(rq2 + (kp0+3)*32 + b);
      #pragma unroll
      for (int jj = 0; jj < 2; ++jj) {
        const int wo = (jj << 9) + kp0;
        c0[jj] = d8(c0[jj], r00,r01,r02,r03, *(const uint4*)(lds_u + 2*1024 + wo));
        c1[jj] = d8(c1[jj], r10,r11,r12,r13, *(const uint4*)(lds_u + 5*1024 + wo));
        c2[jj] = d8(c2[jj], r20,r21,r22,r23, *(const uint4*)(lds_u + 8*1024 + wo));
      }
    }
    #pragma unroll
    for (int jj = 0; jj < 2; ++jj) {
      c0[jj] += __shfl_xor(c0[jj], 32);
      c1[jj] += __shfl_xor(c1[jj], 32);
      c2[jj] += __shfl_xor(c2[jj], 32);
    }
    if (ks == 0) {
      #pragma unroll
      for (int jj = 0; jj < 2; ++jj) {
        my[(0*2+jj)*32 + b] = c0[jj];
        my[(1*2+jj)*32 + b] = c1[jj];
        my[(2*2+jj)*32 + b] = c2[jj];
      }
    }
    __syncthreads();
    if (tid < 32) {
      const int bb = tid;
      #pragma unroll
      for (int l = 0; l < 3; ++l) {
        const bool act = (l == 0) ? act0 : (l == 1) ? act1 : act2;
        if (!act) continue;
        const int tl = (l == 0) ? t0 : (l == 1) ? t1 : t2;
        float hb[2];
        #pragma unroll
        for (int q = 0; q < 2; ++q) {
          float cv = 0.f;
          #pragma unroll
          for (int ww = 0; ww < 8; ++ww)
            cv += scratch[ww * 608 + (l*2 + q)*32 + bb];
          const float g = tanhf(cv + my_gx[l][q]);
          const int j = (bid << 1) + q;
          float* hf = p.hF + l * 32768 + j * 32 + bb;
          const float hp = *hf;
          const float hn = my_z[l][q] * hp + (1.f - my_z[l][q]) * g;
          *hf = hn;
          hb[q] = hn;
          if (tl == 511) p.outHid[bb * 3072 + l * 1024 + j] = hn;
        }
        unsigned* hq = (l == 0) ? hP0 : (l == 1) ? hP1 : hP2;
        storecu(hq + bid * 32 + bb, pack2(hb[0], hb[1]));
      }
    }
    ++phase; gridbar(p.bar, phase, bid);
  } // m

  // final head: t=511
  float ah = 0.f;
  if (bid < 128) {
    #pragma unroll
    for (int i = 0; i < 8; ++i) {
      const int kp0 = (w << 6) + (i << 3) + (ks << 2);
      const unsigned a0 = loadcu(hP2 + (kp0+0)*32 + b);
      const unsigned a1 = loadcu(hP2 + (kp0+1)*32 + b);
      const unsigned a2 = loadcu(hP2 + (kp0+2)*32 + b);
      const unsigned a3 = loadcu(hP2 + (kp0+3)*32 + b);
      const float* wrow = p.Wout + ((size_t)bid << 10) + (kp0 << 1);
      const float4 w0 = *(const float4*)(wrow);
      const float4 w1 = *(const float4*)(wrow + 4);
      ah += blo(a0)*w0.x + bhi(a0)*w0.y + blo(a1)*w0.z + bhi(a1)*w0.w;
      ah += blo(a2)*w1.x + bhi(a2)*w1.y + blo(a3)*w1.z + bhi(a3)*w1.w;
    }
    ah += __shfl_xor(ah, 32);
    if (ks == 0) my[576 + b] = ah;
  }
  __syncthreads();
  if (bid < 128 && tid < 32) {
    float s = 0.f;
    #pragma unroll
    for (int ww = 0; ww < 8; ++ww) s += scratch[ww * 608 + 576 + tid];
    p.out[((size_t)tid << 16) + ((size_t)511 << 7) + bid] = s + p.bout[bid];
  }
}

// Zero hP, rhP, hF, bar: 200,704 dwords (ws poisoned 0xAA before each launch).
__global__ void initWs(unsigned* wsd) {
  const int i = blockIdx.x * 1024 + threadIdx.x;
  if (i < 200704) wsd[i] = 0u;
}

extern "C" void kernel_launch(void* const* d_in, const int* in_sizes, int n_in,
                              void* d_out, int out_size, void* d_ws, size_t ws_size,
                              hipStream_t stream)
{
  GruParams P;
  P.x = (const float*)d_in[0];
  P.Wx[0][0] = (const float*)d_in[1];  P.Wh[0][0] = (const float*)d_in[2];
  P.bias[0][0] = (const float*)d_in[3];
  P.Wx[0][1] = (const float*)d_in[4];  P.Wh[0][1] = (const float*)d_in[5];
  P.bias[0][1] = (const float*)d_in[6];
  P.Wx[0][2] = (const float*)d_in[7];  P.Wh[0][2] = (const float*)d_in[8];
  P.bias[0][2] = (const float*)d_in[9];
  for (int l = 1; l < 3; ++l) {
    const size_t off = (size_t)(l - 1) * 1048576;
    const size_t ob  = (size_t)(l - 1) * 1024;
    P.Wx[l][0] = (const float*)d_in[10] + off; P.Wh[l][0] = (const float*)d_in[11] + off;
    P.bias[l][0] = (const float*)d_in[12] + ob;
    P.Wx[l][1] = (const float*)d_in[13] + off; P.Wh[l][1] = (const float*)d_in[14] + off;
    P.bias[l][1] = (const float*)d_in[15] + ob;
    P.Wx[l][2] = (const float*)d_in[16] + off; P.Wh[l][2] = (const float*)d_in[17] + off;
    P.bias[l][2] = (const float*)d_in[18] + ob;
  }
  P.Wout = (const float*)d_in[19];
  P.bout = (const float*)d_in[20];

  char* ws = (char*)d_ws;
  P.hP  = (unsigned*)ws;                 // 3*16384 uints = 196,608 B
  P.rhP = (unsigned*)(ws + 196608);      // 3*16384 uints = 196,608 B
  P.hF  = (float*)(ws + 393216);         // 3*32768 f32   = 393,216 B
  P.bar = (unsigned*)(ws + 786432);      // 4096 uints
  P.out = (float*)d_out;
  P.outHid = P.out + 2097152;

  hipFuncSetAttribute(reinterpret_cast<const void*>(gruPersist),
                      hipFuncAttributeMaxDynamicSharedMemorySize, LDSB);

  initWs<<<196, 1024, 0, stream>>>((unsigned*)ws);
  gruPersist<<<512, 512, LDSB, stream>>>(P);
}